// Round 1
// 1279.374 us; speedup vs baseline: 1.2130x; 1.2130x over previous
//
#include <hip/hip_runtime.h>
#include <stdint.h>

#define BB   256
#define DD   128
#define KK   8192
#define KP1  8193
#define NDATA 500000
#define MEMELEMS 64000000ULL  // 500000*128
#define KCHUNKS 65            // 65 * 128 k-slots >= 8193
#define SCORE_BLOCKS (KCHUNKS * BB)   // 16640 blocks
// Copy geometry: dst out+1 is only 4B-aligned. Align STORES to 16B by copying
// float4 chunks dst[3+4m..6+4m] <- src[3+4m..6+4m]; head (3 floats) + tail
// (1 float) are scalar edge cases. (64e6 - 4) / 4 chunks per bank:
#define NCHUNK 15999999ULL

// ---------------------------------------------------------------------------
// Fused kernel: (a) gather + dot + exp for both views (unchanged structure:
// 16-lane group per row, 512B coalesced row reads from both banks), then
// (b) a grid-stride float4 slice of the full-bank mv1/mv2 -> out copy.
// The copy is BW-bound, the gather is latency-bound at 26% HBM: interleaving
// them in one dispatch lets the copy use the idle HBM pipe.
// ---------------------------------------------------------------------------
__global__ __launch_bounds__(256) void fused_kernel(
    const float* __restrict__ f_s, const float* __restrict__ f_t,
    const float* __restrict__ mv1, const float* __restrict__ mv2,
    const int* __restrict__ idx, const int* __restrict__ cidx,
    float* __restrict__ sA, float* __restrict__ sB, double* __restrict__ acc,
    float* __restrict__ out1, float* __restrict__ out2, int do_copy)
{
    const int bid = blockIdx.x;
    const int tid = threadIdx.x;
    const int b   = bid / KCHUNKS;
    const int kc  = bid % KCHUNKS;
    const int g   = tid >> 4;   // group 0..15 within block
    const int fl  = tid & 15;   // lane within group

    const float4* fs4 = (const float4*)f_s;
    const float4* ft4 = (const float4*)f_t;
    const float4* m14 = (const float4*)mv1;
    const float4* m24 = (const float4*)mv2;

    const int foff = b * 32 + fl * 2;
    const float4 fsa = fs4[foff], fsb = fs4[foff + 1];
    const float4 fta = ft4[foff], ftb = ft4[foff + 1];

    const float invT = 1.0f / 0.07f;
    float accA = 0.f, accB = 0.f;
    const int kbase = kc * 128;   // 8 iters x 16 groups

    #pragma unroll
    for (int it = 0; it < 8; ++it) {
        const int k = kbase + it * 16 + g;   // group-uniform
        if (k < KP1) {
            const int j  = (k == 0) ? idx[b] : cidx[b * KK + (k - 1)];
            const int ro = j * 32 + fl * 2;
            const float4 a1 = m14[ro], b1 = m14[ro + 1];
            const float4 a2 = m24[ro], b2 = m24[ro + 1];
            float p1 = a2.x*fsa.x + a2.y*fsa.y + a2.z*fsa.z + a2.w*fsa.w
                     + b2.x*fsb.x + b2.y*fsb.y + b2.z*fsb.z + b2.w*fsb.w;   // mv2 . f_s
            float p2 = a1.x*fta.x + a1.y*fta.y + a1.z*fta.z + a1.w*fta.w
                     + b1.x*ftb.x + b1.y*ftb.y + b1.z*ftb.z + b1.w*ftb.w;   // mv1 . f_t
            #pragma unroll
            for (int off = 1; off < 16; off <<= 1) {   // stays within the 16-lane group
                p1 += __shfl_xor(p1, off);
                p2 += __shfl_xor(p2, off);
            }
            if (fl == 0) {
                const float e1 = __expf(p1 * invT);
                const float e2 = __expf(p2 * invT);
                sA[b * KP1 + k] = e1;
                sB[b * KP1 + k] = e2;
                accA += e1;
                accB += e2;
            }
        }
    }

    __shared__ float lA[16], lB[16];
    if (fl == 0) { lA[g] = accA; lB[g] = accB; }
    __syncthreads();
    if (tid == 0) {
        float ta = 0.f, tb = 0.f;
        #pragma unroll
        for (int i = 0; i < 16; ++i) { ta += lA[i]; tb += lB[i]; }
        atomicAdd(&acc[0], (double)ta);
        atomicAdd(&acc[1], (double)tb);
    }

    // ---- copy phase: full-bank mv1/mv2 -> out, 16B-aligned stores ----
    if (do_copy) {
        const size_t stride = (size_t)SCORE_BLOCKS * 256;
        const float* s1 = mv1 + 3;     // misaligned (12 mod 16) loads: legal
        const float* s2 = mv2 + 3;     // at dword alignment on gfx950
        float4* d1 = (float4*)(out1 + 3);  // byte offset 16: aligned
        float4* d2 = (float4*)(out2 + 3);  // (1+64e6)*4+12 ≡ 0 mod 16: aligned
        for (size_t i = (size_t)bid * 256 + tid; i < NCHUNK; i += stride) {
            d1[i] = *(const float4*)(s1 + 4 * i);
            d2[i] = *(const float4*)(s2 + 4 * i);
        }
        if (bid == 0) {
            if (tid < 3) { out1[tid] = mv1[tid]; out2[tid] = mv2[tid]; }
            else if (tid == 3) {
                out1[MEMELEMS - 1] = mv1[MEMELEMS - 1];
                out2[MEMELEMS - 1] = mv2[MEMELEMS - 1];
            }
        }
    }
}

// ---------------------------------------------------------------------------
// NCE contrast loss terms, summed into acc[2].
// x = s / Z, Z = mean(s) * NDATA.
// k==0: log(x/(x+c));  k>0: log(mPn/(x+c));  c = K/N + 1e-7.
// ---------------------------------------------------------------------------
__global__ __launch_bounds__(256) void loss_kernel(
    const float* __restrict__ sA, const float* __restrict__ sB,
    const double* __restrict__ acc, double* __restrict__ lossAcc)
{
    const int b = blockIdx.y;
    const int k = blockIdx.x * 256 + threadIdx.x;

    const double denom = (double)BB * (double)KP1;
    const float invZ1 = (float)(denom / (acc[0] * (double)NDATA));
    const float invZ2 = (float)(denom / (acc[1] * (double)NDATA));
    const float mPn = (float)KK / (float)NDATA;
    const float c   = mPn + 1e-7f;

    float t = 0.f;
    if (k < KP1) {
        const float x1 = sA[b * KP1 + k] * invZ1;
        const float x2 = sB[b * KP1 + k] * invZ2;
        if (k == 0) {
            t = logf(x1 / (x1 + c)) + logf(x2 / (x2 + c));
        } else {
            t = logf(mPn / (x1 + c)) + logf(mPn / (x2 + c));
        }
    }
    #pragma unroll
    for (int off = 1; off < 64; off <<= 1) t += __shfl_xor(t, off);
    __shared__ float ls[4];
    if ((threadIdx.x & 63) == 0) ls[threadIdx.x >> 6] = t;
    __syncthreads();
    if (threadIdx.x == 0)
        atomicAdd(lossAcc, (double)(ls[0] + ls[1] + ls[2] + ls[3]));
}

__global__ void finalize_kernel(const double* __restrict__ acc,
                                float* __restrict__ out)
{
    out[0] = (float)(-acc[2] / (double)BB);
}

// ---------------------------------------------------------------------------
// Momentum scatter-update of the 256 touched rows (after full-bank copy).
// Last-wins for duplicate idx; all 'old' values from the ORIGINAL banks.
// blocks 0..255 -> v1 (f_s), 256..511 -> v2 (f_t).
// ---------------------------------------------------------------------------
__global__ __launch_bounds__(128) void update_kernel(
    const float* __restrict__ mv1, const float* __restrict__ mv2,
    const float* __restrict__ f_s, const float* __restrict__ f_t,
    const int* __restrict__ idx, float* __restrict__ out)
{
    const int v = blockIdx.x >> 8;
    const int b = blockIdx.x & 255;
    const int j = idx[b];
    for (int b2 = b + 1; b2 < BB; ++b2)
        if (idx[b2] == j) return;              // a later b writes this row

    const float* mem = v ? mv2 : mv1;
    const float* f   = v ? f_t : f_s;
    const int t = threadIdx.x;
    const float n = 0.5f * mem[(size_t)j * DD + t] + 0.5f * f[b * DD + t];

    float ss = n * n;
    #pragma unroll
    for (int off = 1; off < 64; off <<= 1) ss += __shfl_xor(ss, off);
    __shared__ float ls[2];
    if ((t & 63) == 0) ls[t >> 6] = ss;
    __syncthreads();
    const float total = ls[0] + ls[1];

    out[1 + (size_t)v * MEMELEMS + (size_t)j * DD + t] = n / sqrtf(total);
}

extern "C" void kernel_launch(void* const* d_in, const int* in_sizes, int n_in,
                              void* d_out, int out_size, void* d_ws, size_t ws_size,
                              hipStream_t stream)
{
    const float* f_s = (const float*)d_in[0];
    const float* f_t = (const float*)d_in[1];
    const float* mv1 = (const float*)d_in[2];
    const float* mv2 = (const float*)d_in[3];
    const int*   idx  = (const int*)d_in[4];
    const int*   cidx = (const int*)d_in[5];
    float* out = (float*)d_out;

    // Scratch: 3 double accumulators + two [B, K+1] float score arrays.
    const size_t sElems = (size_t)BB * KP1;
    double* acc;
    float*  sA;
    int do_copy = 1;
    if (ws_size >= 256 + 2 * sElems * sizeof(float)) {
        acc = (double*)d_ws;
        sA  = (float*)((char*)d_ws + 256);
    } else {
        // Fallback: park scratch in the (not-yet-written) new_v2 output region.
        // In this mode the fused kernel must NOT copy (it would clobber the
        // scratch); use the blit path after the loss consumes the scratch.
        uintptr_t p = (uintptr_t)(out + 1 + (size_t)MEMELEMS);
        p = (p + 255) & ~(uintptr_t)255;
        acc = (double*)p;
        sA  = (float*)(acc + 8);
        do_copy = 0;
    }
    float* sB = sA + sElems;

    hipMemsetAsync(acc, 0, 3 * sizeof(double), stream);

    fused_kernel<<<SCORE_BLOCKS, 256, 0, stream>>>(
        f_s, f_t, mv1, mv2, idx, cidx, sA, sB, acc,
        out + 1, out + 1 + (size_t)MEMELEMS, do_copy);

    dim3 gL(33, BB);    // 33 * 256 >= 8193
    loss_kernel<<<gL, 256, 0, stream>>>(sA, sB, acc, &acc[2]);

    finalize_kernel<<<1, 1, 0, stream>>>(acc, out);

    if (!do_copy) {
        hipMemcpyAsync(out + 1, mv1, (size_t)MEMELEMS * sizeof(float),
                       hipMemcpyDeviceToDevice, stream);
        hipMemcpyAsync(out + 1 + (size_t)MEMELEMS, mv2,
                       (size_t)MEMELEMS * sizeof(float),
                       hipMemcpyDeviceToDevice, stream);
    }

    update_kernel<<<512, 128, 0, stream>>>(mv1, mv2, f_s, f_t, idx, out);
}